// Round 11
// baseline (97.171 us; speedup 1.0000x reference)
//
#include <hip/hip_runtime.h>
#include <math.h>

// LDDMM variational RHS, Gaussian kernel sigma=0.1, B=1, N=8192, D=3.
// out[0:N*3]     = dmom_i = 100 * (x_i * sum_j W_ij - sum_j W_ij x_j)
// out[N*3:2*N*3] = dcp_i  = sum_j K_ij p_j
// K_ij = exp(-|x_i-x_j|^2/(2 sig^2)), W_ij = K_ij*(p_i.p_j), p=clamp(mom,-1,1)
//
// R17: R16's counters: kernel 50us, VALUBusy 42% (=21us issue vs 8us packed
// model -> __builtin_elementwise_fma SCALARIZED; R7/R12 passing rounds used
// asm v_pk_*), occupancy 17.7% (34.8KB LDS caps 2 blocks/CU), conflicts now
// minor (2.1M). Fix: (1) force VOP3P via the R7-proven inline-asm pk ops;
// (2) NO LDS in hot loop -- prep (R15's, passed) writes 256KB jdata pair
// records to ws, main reads them with per-lane coalesced dwordx4 (wave =
// 4KB/group), L2-resident, no barriers in the loop; (3) endgame = wave
// shfl_xor butterfly + 448B LDS combine + 8 write-once stores (R16 pattern).
// Model: max(VALU ~11us, L2 ~8us) -> kernel 12-18us.
// Predict: main 12-20us VALUBusy>=55% conflicts~0; dur 60-67. If main
// >=30us at VALUBusy~40%: latency-bound -> op_sel VGPR cut next round.

#define NPTS    8192
#define N3      (NPTS * 3)
#define THREADS 256
#define NI      4                     // i's per thread
#define IPB     (NI * 2)              // 8 i's per block (2 wave-half groups)
#define NBLK    (NPTS / IPB)          // 1024 blocks
#define NPAIR   (NPTS / 2)            // 4096 j-pairs
#define NSL     128                   // j-slices (s = t & 127)
#define GRP     (NPAIR / NSL)         // 32 pair-groups per thread

// exp(-d2/(2*0.1^2)) = exp2(d2 * (-50*log2(e)))
#define COEF    (-72.134752044448170f)
#define M2COEF  (144.269504088896340f)     // -2*COEF
#define UNSC100 (0.69314718055994531f)     // 100 / M2COEF

#define WS_NEEDED ((size_t)NPAIR * 16 * sizeof(float))  // 256 KB jdata

typedef float v2f __attribute__((ext_vector_type(2)));

__device__ __forceinline__ v2f vsplat(float s) { v2f r; r.x = s; r.y = s; return r; }

// VOP3P packed fp32, R7-proven inline asm (passed on this harness).
__device__ __forceinline__ v2f pk_fma(v2f a, v2f b, v2f c) {
    v2f d;
    asm("v_pk_fma_f32 %0, %1, %2, %3" : "=v"(d) : "v"(a), "v"(b), "v"(c));
    return d;
}
__device__ __forceinline__ v2f pk_add(v2f a, v2f b) {
    v2f d;
    asm("v_pk_add_f32 %0, %1, %2" : "=v"(d) : "v"(a), "v"(b));
    return d;
}
__device__ __forceinline__ v2f pk_mul(v2f a, v2f b) {
    v2f d;
    asm("v_pk_mul_f32 %0, %1, %2" : "=v"(d) : "v"(a), "v"(b));
    return d;
}

__device__ __forceinline__ float fast_exp2(float x) {
#if __has_builtin(__builtin_amdgcn_exp2f)
    return __builtin_amdgcn_exp2f(x);
#else
    return exp2f(x);
#endif
}

__device__ __forceinline__ float clamp1(float v) {
    return fminf(fmaxf(v, -1.0f), 1.0f);
}

// jdata pair record (4 float4 = 64B per pair P; j0=2P, j1=2P+1):
//  [0] = {M2*x0(j0), M2*x0(j1), M2*x1(j0), M2*x1(j1)}
//  [1] = {M2*x2(j0), M2*x2(j1), cj(j0),    cj(j1)}      cj = COEF*|xj|^2
//  [2] = {p0(j0),    p0(j1),    p1(j0),    p1(j1)}
//  [3] = {p2(j0),    p2(j1),    0,         0}
__global__ __launch_bounds__(256) void lddmm_prep(const float* __restrict__ mom,
                                                  const float* __restrict__ cp,
                                                  float4* __restrict__ jd4) {
    const int P  = (int)blockIdx.x * 256 + (int)threadIdx.x;
    const int j0 = 2 * P;
    const int j1 = j0 + 1;
    const float xa0 = cp[j0 * 3 + 0], xa1 = cp[j0 * 3 + 1], xa2 = cp[j0 * 3 + 2];
    const float xb0 = cp[j1 * 3 + 0], xb1 = cp[j1 * 3 + 1], xb2 = cp[j1 * 3 + 2];
    jd4[4 * P + 0] = make_float4(M2COEF * xa0, M2COEF * xb0,
                                 M2COEF * xa1, M2COEF * xb1);
    jd4[4 * P + 1] = make_float4(M2COEF * xa2, M2COEF * xb2,
                                 COEF * (xa0 * xa0 + xa1 * xa1 + xa2 * xa2),
                                 COEF * (xb0 * xb0 + xb1 * xb1 + xb2 * xb2));
    jd4[4 * P + 2] = make_float4(clamp1(mom[j0 * 3 + 0]), clamp1(mom[j1 * 3 + 0]),
                                 clamp1(mom[j0 * 3 + 1]), clamp1(mom[j1 * 3 + 1]));
    jd4[4 * P + 3] = make_float4(clamp1(mom[j0 * 3 + 2]), clamp1(mom[j1 * 3 + 2]),
                                 0.0f, 0.0f);
}

// Main: block owns IPB=8 i's. Wave-half group it=t>>7 covers i's
// ibase..ibase+3; slice s=t&127 covers pairs P = g*128 + s, g=0..31.
// Hot loop: 4 coalesced dwordx4 per group (wave reads 4KB contiguous),
// zero LDS, zero barriers. Endgame: shfl_xor butterfly + tiny LDS combine.
__global__ __launch_bounds__(THREADS) void lddmm_main(const float* __restrict__ mom,
                                                      const float* __restrict__ cp,
                                                      const float4* __restrict__ jd4,
                                                      float* __restrict__ out) {
    const int t  = (int)threadIdx.x;
    const int it = t >> 7;               // wave-half group 0/1
    const int s  = t & 127;              // j-slice
    const int ibase = (int)blockIdx.x * IPB + it * NI;

    // i-side loop-invariant splats.
    v2f sx0[NI], sx1[NI], sx2[NI], sci[NI], sp0[NI], sp1[NI], sp2[NI];
#pragma unroll
    for (int n = 0; n < NI; ++n) {
        const int i = ibase + n;
        const float x0 = cp[i * 3 + 0], x1 = cp[i * 3 + 1], x2 = cp[i * 3 + 2];
        sx0[n] = vsplat(x0);
        sx1[n] = vsplat(x1);
        sx2[n] = vsplat(x2);
        sci[n] = vsplat(COEF * (x0 * x0 + x1 * x1 + x2 * x2));
        sp0[n] = vsplat(clamp1(mom[i * 3 + 0]));
        sp1[n] = vsplat(clamp1(mom[i * 3 + 1]));
        sp2[n] = vsplat(clamp1(mom[i * 3 + 2]));
    }

    v2f dcp0[NI], dcp1[NI], dcp2[NI], wsum[NI], wx0[NI], wx1[NI], wx2[NI];
#pragma unroll
    for (int n = 0; n < NI; ++n) {
        dcp0[n] = vsplat(0.f); dcp1[n] = vsplat(0.f); dcp2[n] = vsplat(0.f);
        wsum[n] = vsplat(0.f);
        wx0[n] = vsplat(0.f); wx1[n] = vsplat(0.f); wx2[n] = vsplat(0.f);
    }

#pragma unroll 2
    for (int g = 0; g < GRP; ++g) {
        const int P = g * NSL + s;
        const float4 A = jd4[4 * P + 0];   // coalesced: wave = 4KB contiguous
        const float4 B = jd4[4 * P + 1];
        const float4 C = jd4[4 * P + 2];
        const float4 D = jd4[4 * P + 3];
        v2f xj0p; xj0p.x = A.x; xj0p.y = A.y;
        v2f xj1p; xj1p.x = A.z; xj1p.y = A.w;
        v2f xj2p; xj2p.x = B.x; xj2p.y = B.y;
        v2f cjp;  cjp.x  = B.z; cjp.y  = B.w;
        v2f pj0p; pj0p.x = C.x; pj0p.y = C.y;
        v2f pj1p; pj1p.x = C.z; pj1p.y = C.w;
        v2f pj2p; pj2p.x = D.x; pj2p.y = D.y;
#pragma unroll
        for (int n = 0; n < NI; ++n) {
            // arg = ci + cj + xi.(M2*xj) = COEF*d2  (packed over 2 j's)
            v2f arg = pk_add(sci[n], cjp);
            arg = pk_fma(sx0[n], xj0p, arg);
            arg = pk_fma(sx1[n], xj1p, arg);
            arg = pk_fma(sx2[n], xj2p, arg);
            v2f K;
            K.x = fast_exp2(arg.x);
            K.y = fast_exp2(arg.y);
            v2f pd = pk_mul(sp0[n], pj0p);
            pd = pk_fma(sp1[n], pj1p, pd);
            pd = pk_fma(sp2[n], pj2p, pd);
            const v2f W = pk_mul(K, pd);
            dcp0[n] = pk_fma(K, pj0p, dcp0[n]);
            dcp1[n] = pk_fma(K, pj1p, dcp1[n]);
            dcp2[n] = pk_fma(K, pj2p, dcp2[n]);
            wsum[n] = pk_add(wsum[n], W);
            wx0[n] = pk_fma(W, xj0p, wx0[n]);   // M2COEF-scaled
            wx1[n] = pk_fma(W, xj1p, wx1[n]);
            wx2[n] = pk_fma(W, xj2p, wx2[n]);
        }
    }

    // Fold packed halves; full-wave butterfly (all 64 lanes of a wave hold
    // partials for the SAME 4 i's).
    float r[NI][7];
#pragma unroll
    for (int n = 0; n < NI; ++n) {
        r[n][0] = dcp0[n].x + dcp0[n].y;
        r[n][1] = dcp1[n].x + dcp1[n].y;
        r[n][2] = dcp2[n].x + dcp2[n].y;
        r[n][3] = wsum[n].x + wsum[n].y;
        r[n][4] = wx0[n].x + wx0[n].y;
        r[n][5] = wx1[n].x + wx1[n].y;
        r[n][6] = wx2[n].x + wx2[n].y;
    }
#pragma unroll
    for (int m = 1; m <= 32; m <<= 1) {
#pragma unroll
        for (int n = 0; n < NI; ++n) {
#pragma unroll
            for (int v = 0; v < 7; ++v) {
                r[n][v] += __shfl_xor(r[n][v], m);
            }
        }
    }

    // Cross-wave combine: lane 0 of each of the 4 waves deposits 28 floats.
    __shared__ float rb[4 * NI * 7];     // 448 B
    const int wave = t >> 6;
    if ((t & 63) == 0) {
#pragma unroll
        for (int n = 0; n < NI; ++n) {
#pragma unroll
            for (int v = 0; v < 7; ++v) {
                rb[wave * (NI * 7) + n * 7 + v] = r[n][v];
            }
        }
    }
    __syncthreads();
    if (t < IPB) {
        // waves 0,1 hold i's base+0..3; waves 2,3 hold base+4..7
        const int w0 = (t < NI) ? 0 : 2;
        const int n  = t & (NI - 1);
        float f[7];
#pragma unroll
        for (int v = 0; v < 7; ++v) {
            f[v] = rb[w0 * (NI * 7) + n * 7 + v] + rb[(w0 + 1) * (NI * 7) + n * 7 + v];
        }
        const int i = (int)blockIdx.x * IPB + t;
        const float x0 = cp[i * 3 + 0], x1 = cp[i * 3 + 1], x2 = cp[i * 3 + 2];
        out[N3 + i * 3 + 0] = f[0];
        out[N3 + i * 3 + 1] = f[1];
        out[N3 + i * 3 + 2] = f[2];
        // dmom = 100*xi*wsum - (100/M2COEF)*wxs
        out[i * 3 + 0] = fmaf(100.0f * x0, f[3], -UNSC100 * f[4]);
        out[i * 3 + 1] = fmaf(100.0f * x1, f[3], -UNSC100 * f[5]);
        out[i * 3 + 2] = fmaf(100.0f * x2, f[3], -UNSC100 * f[6]);
    }
}

// ---- fallback (atomics into d_out) if ws_size < 256KB; never runs in this
// harness (ws is 268MB) -- dead code retained from the passing R0 round. ----
#define FJC   32
#define FJLEN (NPTS / FJC)
__global__ __launch_bounds__(256) void lddmm_pairs_atomic(const float* __restrict__ mom,
                                                          const float* __restrict__ cp,
                                                          float* __restrict__ out) {
    const int ib = (int)blockIdx.x / FJC;
    const int jc = (int)blockIdx.x % FJC;
    const int t  = (int)threadIdx.x;
    const int i  = ib * 256 + t;

    const float xi0 = cp[i * 3 + 0], xi1 = cp[i * 3 + 1], xi2 = cp[i * 3 + 2];
    const float pi0 = clamp1(mom[i * 3 + 0]), pi1 = clamp1(mom[i * 3 + 1]),
                pi2 = clamp1(mom[i * 3 + 2]);

    __shared__ float4 shx[FJLEN];
    __shared__ float4 shp[FJLEN];
    {
        const int j = jc * FJLEN + t;
        shx[t] = make_float4(cp[j * 3 + 0], cp[j * 3 + 1], cp[j * 3 + 2], 0.0f);
        shp[t] = make_float4(clamp1(mom[j * 3 + 0]), clamp1(mom[j * 3 + 1]),
                             clamp1(mom[j * 3 + 2]), 0.0f);
    }
    __syncthreads();

    float dcp0 = 0.f, dcp1 = 0.f, dcp2 = 0.f, wsum = 0.f, wx0 = 0.f, wx1 = 0.f, wx2 = 0.f;
#pragma unroll 4
    for (int jj = 0; jj < FJLEN; ++jj) {
        const float4 xj = shx[jj];
        const float4 pj = shp[jj];
        const float dx0 = xi0 - xj.x, dx1 = xi1 - xj.y, dx2 = xi2 - xj.z;
        const float d2  = dx0 * dx0 + dx1 * dx1 + dx2 * dx2;
        const float K   = fast_exp2(d2 * COEF);
        const float pd  = pi0 * pj.x + pi1 * pj.y + pi2 * pj.z;
        const float W   = K * pd;
        dcp0 += K * pj.x; dcp1 += K * pj.y; dcp2 += K * pj.z;
        wsum += W;
        wx0 += W * xj.x; wx1 += W * xj.y; wx2 += W * xj.z;
    }
    atomicAdd(&out[i * 3 + 0], 100.0f * (xi0 * wsum - wx0));
    atomicAdd(&out[i * 3 + 1], 100.0f * (xi1 * wsum - wx1));
    atomicAdd(&out[i * 3 + 2], 100.0f * (xi2 * wsum - wx2));
    atomicAdd(&out[N3 + i * 3 + 0], dcp0);
    atomicAdd(&out[N3 + i * 3 + 1], dcp1);
    atomicAdd(&out[N3 + i * 3 + 2], dcp2);
}

extern "C" void kernel_launch(void* const* d_in, const int* in_sizes, int n_in,
                              void* d_out, int out_size, void* d_ws, size_t ws_size,
                              hipStream_t stream) {
    const float* mom = (const float*)d_in[0];
    const float* cp  = (const float*)d_in[1];
    float* out = (float*)d_out;

    if (ws_size >= WS_NEEDED) {
        float4* jd4 = (float4*)d_ws;
        hipLaunchKernelGGL(lddmm_prep, dim3(NPAIR / 256), dim3(256), 0, stream,
                           mom, cp, jd4);
        hipLaunchKernelGGL(lddmm_main, dim3(NBLK), dim3(THREADS), 0, stream,
                           mom, cp, jd4, out);
    } else {
        hipMemsetAsync(out, 0, (size_t)out_size * sizeof(float), stream);
        hipLaunchKernelGGL(lddmm_pairs_atomic, dim3((NPTS / 256) * FJC), dim3(256), 0,
                           stream, mom, cp, out);
    }
}

// Round 15
// 94.899 us; speedup vs baseline: 1.0239x; 1.0239x over previous
//
#include <hip/hip_runtime.h>
#include <math.h>

// LDDMM variational RHS, Gaussian kernel sigma=0.1, B=1, N=8192, D=3.
// out[0:N*3]     = dmom_i = 100 * (x_i * sum_j W_ij - sum_j W_ij x_j)
// out[N*3:2*N*3] = dcp_i  = sum_j K_ij p_j
// K_ij = exp(-|x_i-x_j|^2/(2 sig^2)), W_ij = K_ij*(p_i.p_j), p=clamp(mom,-1,1)
//
// R21: R20 (ws-free, audited) failed with the same ~1e5 garbage -> the
// ws-poison-race theory is dead; the failure mode is an unobservable,
// novelty-correlated gremlin (6/13 attempts, never on a proven structure;
// R12 byte-exact control passed). Policy: proven components only.
// This round: R15 (88.5us best: prep + uniform-load partial + reduce) with
// the ONE proven lever not yet applied -- occupancy. JC 64->128 doubles the
// partial grid to 2048 blocks (8 waves/SIMD, was 4) at unchanged total VALU
// work; R15's partial runs ~35us vs a ~15.4us issue floor (55% latency
// stall, same disease R14/R16/R17 counters showed). The JC=128 partial +
// 8-sub reduce pair is exactly round-1's PASSING R7 config; prep + uniform
// jd4 loads is PASSING R15. Recombination, not novelty.
// Predict: pass; partial 20-26us, reduce ~5.5, dur 75-81 (new best). If
// partial flat ~35 despite 2x occupancy: uniform-load stall is intrinsic
// -> ~88us is the practical floor (fill 43.6 untouchable), declare next.

#define NPTS 8192
#define N3   (NPTS * 3)
#define BI   256
#define IBLK (NPTS / (BI * 2))       // 16 i-blocks (2 i's per thread, packed)
#define JC   128                     // j-chunks -> partial grid = 2048
#define JLEN (NPTS / JC)             // 64 j's per chunk

// exp(-d2/(2*0.1^2)) = exp2(d2 * (-50*log2(e)))
#define COEF    (-72.134752044448170f)
#define M2COEF  (144.269504088896340f)     // -2*COEF
#define UNSC100 (0.69314718055994531f)     // 100 / M2COEF

#define JDF      (NPTS * 8)                              // jdata floats (65536)
#define WS_NEEDED ((size_t)(JDF + (size_t)JC * NPTS * 8) * sizeof(float))  // ~33.8 MB

typedef float v2f __attribute__((ext_vector_type(2)));

__device__ __forceinline__ v2f vsplat(float s) { v2f r; r.x = s; r.y = s; return r; }

__device__ __forceinline__ v2f pkfma(v2f a, v2f b, v2f c) {
#if __has_builtin(__builtin_elementwise_fma)
    return __builtin_elementwise_fma(a, b, c);
#else
    v2f r; r.x = fmaf(a.x, b.x, c.x); r.y = fmaf(a.y, b.y, c.y); return r;
#endif
}

__device__ __forceinline__ float fast_exp2(float x) {
#if __has_builtin(__builtin_amdgcn_exp2f)
    return __builtin_amdgcn_exp2f(x);
#else
    return exp2f(x);
#endif
}

__device__ __forceinline__ float clamp1(float v) {
    return fminf(fmaxf(v, -1.0f), 1.0f);
}

// ---- prep (R15 verbatim, passed): jdata[j] = {M2*x, cj | clamp(p), 0} ----
__global__ __launch_bounds__(256) void lddmm_prep(const float* __restrict__ mom,
                                                  const float* __restrict__ cp,
                                                  float4* __restrict__ jd4) {
    const int j = (int)blockIdx.x * 256 + (int)threadIdx.x;
    const float x0 = cp[j * 3 + 0], x1 = cp[j * 3 + 1], x2 = cp[j * 3 + 2];
    jd4[2 * j + 0] = make_float4(M2COEF * x0, M2COEF * x1, M2COEF * x2,
                                 COEF * (x0 * x0 + x1 * x1 + x2 * x2));
    jd4[2 * j + 1] = make_float4(clamp1(mom[j * 3 + 0]), clamp1(mom[j * 3 + 1]),
                                 clamp1(mom[j * 3 + 2]), 0.0f);
}

// wpart layout: wpart[((c*NPTS)+i)*8 + k], k=0..3: dcp0,dcp1,dcp2,wsum
//                                         k=4..7: wxs0,wxs1,wxs2,0
// (R15's partial verbatim, passed; only JC doubled -> JLEN=64, grid 2048)
__global__ __launch_bounds__(BI, 4) void lddmm_partial(const float* __restrict__ mom,
                                                       const float* __restrict__ cp,
                                                       const float4* __restrict__ jd4,
                                                       float* __restrict__ wpart) {
    const int ib = (int)blockIdx.x / JC;
    const int jc = (int)blockIdx.x % JC;
    const int t  = (int)threadIdx.x;
    const int i0 = ib * (BI * 2) + t;     // component .x
    const int i1 = i0 + BI;               // component .y

    // i-side data packed: {i0-value, i1-value}
    v2f xi0, xi1, xi2, ci, pi0, pi1, pi2;
    {
        const float a0 = cp[i0 * 3 + 0], a1 = cp[i0 * 3 + 1], a2 = cp[i0 * 3 + 2];
        const float b0 = cp[i1 * 3 + 0], b1 = cp[i1 * 3 + 1], b2 = cp[i1 * 3 + 2];
        xi0.x = a0; xi0.y = b0;
        xi1.x = a1; xi1.y = b1;
        xi2.x = a2; xi2.y = b2;
        ci.x = COEF * (a0 * a0 + a1 * a1 + a2 * a2);
        ci.y = COEF * (b0 * b0 + b1 * b1 + b2 * b2);
        pi0.x = clamp1(mom[i0 * 3 + 0]); pi0.y = clamp1(mom[i1 * 3 + 0]);
        pi1.x = clamp1(mom[i0 * 3 + 1]); pi1.y = clamp1(mom[i1 * 3 + 1]);
        pi2.x = clamp1(mom[i0 * 3 + 2]); pi2.y = clamp1(mom[i1 * 3 + 2]);
    }

    v2f dcp0 = vsplat(0.f), dcp1 = vsplat(0.f), dcp2 = vsplat(0.f);
    v2f wsum = vsplat(0.f);
    v2f wx0 = vsplat(0.f), wx1 = vsplat(0.f), wx2 = vsplat(0.f);

    const int jbase = jc * JLEN;

#pragma unroll 8
    for (int jj = 0; jj < JLEN; ++jj) {
        // wave-uniform index -> scalar/L1-broadcast load
        const float4 xj = jd4[(jbase + jj) * 2 + 0];
        const float4 pj = jd4[(jbase + jj) * 2 + 1];

        // arg = ci + cj + dot(xi, M2COEF*xj) = COEF*d2  (1 pk_add + 3 pk_fma)
        v2f arg = ci + vsplat(xj.w);
        arg = pkfma(xi2, vsplat(xj.z), arg);
        arg = pkfma(xi1, vsplat(xj.y), arg);
        arg = pkfma(xi0, vsplat(xj.x), arg);
        v2f K;                               // 2 trans
        K.x = fast_exp2(arg.x);
        K.y = fast_exp2(arg.y);
        v2f pd = pi0 * vsplat(pj.x);         // 1 pk_mul + 2 pk_fma
        pd = pkfma(pi1, vsplat(pj.y), pd);
        pd = pkfma(pi2, vsplat(pj.z), pd);
        const v2f W = K * pd;                // 1 pk_mul
        dcp0 = pkfma(K, vsplat(pj.x), dcp0); // 3 pk_fma
        dcp1 = pkfma(K, vsplat(pj.y), dcp1);
        dcp2 = pkfma(K, vsplat(pj.z), dcp2);
        wsum = wsum + W;                     // 1 pk_add
        wx0 = pkfma(W, vsplat(xj.x), wx0);   // 3 pk_fma (M2COEF-scaled)
        wx1 = pkfma(W, vsplat(xj.y), wx1);
        wx2 = pkfma(W, vsplat(xj.z), wx2);
    }

    float4* oa = (float4*)(wpart + ((size_t)(jc * NPTS) + i0) * 8);
    oa[0] = make_float4(dcp0.x, dcp1.x, dcp2.x, wsum.x);
    oa[1] = make_float4(wx0.x, wx1.x, wx2.x, 0.0f);
    float4* ob = (float4*)(wpart + ((size_t)(jc * NPTS) + i1) * 8);
    ob[0] = make_float4(dcp0.y, dcp1.y, dcp2.y, wsum.y);
    ob[1] = make_float4(wx0.y, wx1.y, wx2.y, 0.0f);
}

// 8 threads per i (round-1 R7's reduce verbatim, passed with JC=128):
// sub = (cpart<<1)|half; cpart 0..3 sums JC/4=32 chunks of one float4 slot;
// xor-2/xor-4 combine cparts; xor-1 hands wsum from half0 to half1.
// dmom = 100*xi*wsum - (100/M2COEF)*wxs.
__global__ __launch_bounds__(256) void lddmm_reduce(const float* __restrict__ wpart,
                                                    const float* __restrict__ cp,
                                                    float* __restrict__ out) {
    const int tid   = (int)blockIdx.x * 256 + (int)threadIdx.x;
    const int i     = tid >> 3;
    const int sub   = tid & 7;
    const int half  = sub & 1;
    const int cpart = sub >> 1;

    float4 acc = make_float4(0.f, 0.f, 0.f, 0.f);
    const int c0 = cpart * (JC / 4);
#pragma unroll 4
    for (int c = c0; c < c0 + JC / 4; ++c) {
        const float4 v = ((const float4*)(wpart + ((size_t)(c * NPTS) + i) * 8))[half];
        acc.x += v.x; acc.y += v.y; acc.z += v.z; acc.w += v.w;
    }
    acc.x += __shfl_xor(acc.x, 2);
    acc.y += __shfl_xor(acc.y, 2);
    acc.z += __shfl_xor(acc.z, 2);
    acc.w += __shfl_xor(acc.w, 2);
    acc.x += __shfl_xor(acc.x, 4);
    acc.y += __shfl_xor(acc.y, 4);
    acc.z += __shfl_xor(acc.z, 4);
    acc.w += __shfl_xor(acc.w, 4);
    const float wsum = __shfl_xor(acc.w, 1);
    if (sub == 0) {
        out[N3 + i * 3 + 0] = acc.x;
        out[N3 + i * 3 + 1] = acc.y;
        out[N3 + i * 3 + 2] = acc.z;
    } else if (sub == 1) {
        const float xi0 = cp[i * 3 + 0];
        const float xi1 = cp[i * 3 + 1];
        const float xi2 = cp[i * 3 + 2];
        out[i * 3 + 0] = fmaf(100.0f * xi0, wsum, -UNSC100 * acc.x);
        out[i * 3 + 1] = fmaf(100.0f * xi1, wsum, -UNSC100 * acc.y);
        out[i * 3 + 2] = fmaf(100.0f * xi2, wsum, -UNSC100 * acc.z);
    }
}

// ---- fallback (atomics into d_out) if ws_size < WS_NEEDED; never runs in
// this harness (ws is 268MB) -- dead code retained from the passing R0. ----
#define FJC   32
#define FJLEN (NPTS / FJC)
__global__ __launch_bounds__(BI) void lddmm_pairs_atomic(const float* __restrict__ mom,
                                                         const float* __restrict__ cp,
                                                         float* __restrict__ out) {
    const int ib = (int)blockIdx.x / FJC;
    const int jc = (int)blockIdx.x % FJC;
    const int t  = (int)threadIdx.x;
    const int i  = ib * BI + t;

    const float xi0 = cp[i * 3 + 0], xi1 = cp[i * 3 + 1], xi2 = cp[i * 3 + 2];
    const float pi0 = clamp1(mom[i * 3 + 0]), pi1 = clamp1(mom[i * 3 + 1]),
                pi2 = clamp1(mom[i * 3 + 2]);

    __shared__ float4 shx[FJLEN];
    __shared__ float4 shp[FJLEN];
    {
        const int j = jc * FJLEN + t;
        shx[t] = make_float4(cp[j * 3 + 0], cp[j * 3 + 1], cp[j * 3 + 2], 0.0f);
        shp[t] = make_float4(clamp1(mom[j * 3 + 0]), clamp1(mom[j * 3 + 1]),
                             clamp1(mom[j * 3 + 2]), 0.0f);
    }
    __syncthreads();

    float dcp0 = 0.f, dcp1 = 0.f, dcp2 = 0.f, wsum = 0.f, wx0 = 0.f, wx1 = 0.f, wx2 = 0.f;
#pragma unroll 4
    for (int jj = 0; jj < FJLEN; ++jj) {
        const float4 xj = shx[jj];
        const float4 pj = shp[jj];
        const float dx0 = xi0 - xj.x, dx1 = xi1 - xj.y, dx2 = xi2 - xj.z;
        const float d2  = dx0 * dx0 + dx1 * dx1 + dx2 * dx2;
        const float K   = fast_exp2(d2 * COEF);
        const float pd  = pi0 * pj.x + pi1 * pj.y + pi2 * pj.z;
        const float W   = K * pd;
        dcp0 += K * pj.x; dcp1 += K * pj.y; dcp2 += K * pj.z;
        wsum += W;
        wx0 += W * xj.x; wx1 += W * xj.y; wx2 += W * xj.z;
    }
    atomicAdd(&out[i * 3 + 0], 100.0f * (xi0 * wsum - wx0));
    atomicAdd(&out[i * 3 + 1], 100.0f * (xi1 * wsum - wx1));
    atomicAdd(&out[i * 3 + 2], 100.0f * (xi2 * wsum - wx2));
    atomicAdd(&out[N3 + i * 3 + 0], dcp0);
    atomicAdd(&out[N3 + i * 3 + 1], dcp1);
    atomicAdd(&out[N3 + i * 3 + 2], dcp2);
}

extern "C" void kernel_launch(void* const* d_in, const int* in_sizes, int n_in,
                              void* d_out, int out_size, void* d_ws, size_t ws_size,
                              hipStream_t stream) {
    const float* mom = (const float*)d_in[0];
    const float* cp  = (const float*)d_in[1];
    float* out = (float*)d_out;

    if (ws_size >= WS_NEEDED) {
        float* ws = (float*)d_ws;
        float4* jd4   = (float4*)ws;           // 256 KB
        float*  wpart = ws + JDF;              // 33.55 MB
        hipLaunchKernelGGL(lddmm_prep, dim3(NPTS / 256), dim3(256), 0, stream,
                           mom, cp, jd4);
        hipLaunchKernelGGL(lddmm_partial, dim3(IBLK * JC), dim3(BI), 0, stream,
                           mom, cp, jd4, wpart);
        hipLaunchKernelGGL(lddmm_reduce, dim3(NPTS * 8 / 256), dim3(256), 0, stream,
                           wpart, cp, out);
    } else {
        hipMemsetAsync(out, 0, (size_t)out_size * sizeof(float), stream);
        hipLaunchKernelGGL(lddmm_pairs_atomic, dim3((NPTS / BI) * FJC), dim3(BI), 0,
                           stream, mom, cp, out);
    }
}